// Round 5
// baseline (645.234 us; speedup 1.0000x reference)
//
#include <hip/hip_runtime.h>
#include <math.h>

#define B    256
#define I_   1152
#define O    10
#define DIN  8
#define OE   160          // O*DOUT
#define XROW 9216         // I*Din = K of the s-GEMM
#define WROW 1280         // O*Din*Dout
#define PSPLIT 72         // split-K partials (spart: 72 ic x 2 mb = 144 blocks)
#define CHUNK  16         // i per spart block
#define LROW   40         // padded LDS row stride (shorts), K-window 32 + 8 pad
#define NBLK   256        // grid size; <= 256 CUs and 46KB LDS -> all resident

typedef __attribute__((ext_vector_type(8))) short short8;
typedef __attribute__((ext_vector_type(4))) float floatx4;

__device__ __forceinline__ unsigned short f2bf(float f) {
    unsigned u = __builtin_bit_cast(unsigned, f);
    u += 0x7fffu + ((u >> 16) & 1u);          // RNE
    return (unsigned short)(u >> 16);
}
__device__ __forceinline__ float bf2f(unsigned short h) {
    unsigned u = ((unsigned)h) << 16;
    return __builtin_bit_cast(float, u);
}
__device__ __forceinline__ void split8(const float* s, short8& hv, short8& lv) {
#pragma unroll
    for (int d = 0; d < 8; ++d) {
        unsigned short h = f2bf(s[d]);
        hv[d] = (short)h;
        lv[d] = (short)f2bf(s[d] - bf2f(h));
    }
}

// ---------------------------------------------------------------------------
// Manual grid barrier (no cooperative launch). Generation-counter scheme:
// last arriver resets cnt then releases gen. All 256 blocks are provably
// co-resident (256 blocks / 256 CUs, 46KB LDS), so no deadlock.
// __threadfence() both sides = device-scope release/acquire across XCD L2s.
// ---------------------------------------------------------------------------
__device__ __forceinline__ void grid_bar(int* cnt, int* gen) {
    __syncthreads();
    if (threadIdx.x == 0) {
        __threadfence();
        int g = __hip_atomic_load(gen, __ATOMIC_RELAXED, __HIP_MEMORY_SCOPE_AGENT);
        int prev = __hip_atomic_fetch_add(cnt, 1, __ATOMIC_ACQ_REL, __HIP_MEMORY_SCOPE_AGENT);
        if (prev == NBLK - 1) {
            __hip_atomic_store(cnt, 0, __ATOMIC_RELAXED, __HIP_MEMORY_SCOPE_AGENT);
            __hip_atomic_fetch_add(gen, 1, __ATOMIC_RELEASE, __HIP_MEMORY_SCOPE_AGENT);
        } else {
            while (__hip_atomic_load(gen, __ATOMIC_RELAXED, __HIP_MEMORY_SCOPE_AGENT) == g)
                __builtin_amdgcn_s_sleep(2);
        }
        __threadfence();
    }
    __syncthreads();
}

// ---------------------------------------------------------------------------
// AGREE phase: block owns NI i's. Thread t<160 owns column oe=t.
//   G[i,d,oe] = sum_b x[b,i,d]*v[b,oe]  -- x via wave-uniform s_load, v one
//   coalesced vector load per b; zero LDS in the hot loop.
//   agree[i,o] = (1/B) sum_{d,e} W[i,o,d,e]*G[i,d,oe]; b+=agree; c=softmax(b)
// ---------------------------------------------------------------------------
template<int NI>
__device__ __forceinline__ void agree_phase(
    const float* __restrict__ x, const float* __restrict__ W,
    const float* __restrict__ v, float* __restrict__ cbuf,
    float* bl, float (*brow)[16], int iStart, int t)
{
    const int o = t >> 4, e = t & 15;
    if (t < OE) {
        float acc[NI][8];
#pragma unroll
        for (int ii = 0; ii < NI; ++ii)
#pragma unroll
            for (int d = 0; d < 8; ++d) acc[ii][d] = 0.f;

#pragma unroll 4
        for (int b = 0; b < B; ++b) {
            float vv = v[b * OE + t];                              // coalesced
            const float* xr = x + (size_t)b * XROW + iStart * DIN; // uniform
#pragma unroll
            for (int ii = 0; ii < NI; ++ii)
#pragma unroll
                for (int d = 0; d < 8; ++d)
                    acc[ii][d] = fmaf(xr[ii * 8 + d], vv, acc[ii][d]);
        }
#pragma unroll
        for (int ii = 0; ii < NI; ++ii) {
            const float* wr = W + (size_t)(iStart + ii) * WROW + o * 128 + e;
            float p = 0.f;
#pragma unroll
            for (int d = 0; d < 8; ++d) p = fmaf(wr[d * 16], acc[ii][d], p);
            p += __shfl_xor(p, 8, 16);
            p += __shfl_xor(p, 4, 16);
            p += __shfl_xor(p, 2, 16);
            p += __shfl_xor(p, 1, 16);
            bl[ii] += p * (1.f / 256.f);       // uniform within 16-lane group
            if (e == 0) brow[ii][o] = bl[ii];
        }
    }
    __syncthreads();
    if (t < NI) {
        float m = brow[t][0];
#pragma unroll
        for (int oo = 1; oo < O; ++oo) m = fmaxf(m, brow[t][oo]);
        float ex[O], sum = 0.f;
#pragma unroll
        for (int oo = 0; oo < O; ++oo) { ex[oo] = __expf(brow[t][oo] - m); sum += ex[oo]; }
        float inv = 1.f / sum;
#pragma unroll
        for (int oo = 0; oo < O; ++oo) cbuf[(iStart + t) * O + oo] = ex[oo] * inv;
    }
}

// ---------------------------------------------------------------------------
// Fully-fused CapsNet routing: one plain kernel, 256 blocks x 256 threads,
// manual grid barriers between phases.
//   per iter: SPART (144 blocks, MFMA bf16 hi/lo split-K GEMM, K-window 32)
//             -> bar -> VRED (160 blocks, sum 72 partials + squash)
//             -> bar -> AGREE (all 256 blocks, 4-5 i each) -> bar
// iter-0 spart also performs the x fp32->bf16 h/l split (its x-tiles exactly
// partition x).
// ---------------------------------------------------------------------------
__global__ void __launch_bounds__(256)
capsnet_fused(const float* __restrict__ x, const float* __restrict__ W,
              float* __restrict__ out,
              unsigned short* __restrict__ xh, unsigned short* __restrict__ xl,
              float* __restrict__ cbuf, float* __restrict__ vbuf,
              float* __restrict__ sp, int* __restrict__ bar)
{
    __shared__ unsigned short sWh[OE * LROW], sWl[OE * LROW];     // 12.5 KB x2
    __shared__ unsigned short sXh[128 * LROW], sXl[128 * LROW];   // 10 KB x2
    __shared__ float sBrow[5][16];

    int* bcnt = bar;
    int* bgen = bar + 16;

    const int blk = blockIdx.x;
    const int t   = threadIdx.x;

    float bl[5] = {0.f, 0.f, 0.f, 0.f, 0.f};   // routing logits (registers)
    int iStart, ni;
    if (blk < 128) { ni = 5; iStart = blk * 5; }
    else           { ni = 4; iStart = 640 + (blk - 128) * 4; }

    for (int iter = 0; iter < 3; ++iter) {
        const int first = (iter == 0);

        // ================= SPART =================
        if (blk < 144) {
            const int ic = blk >> 1;
            const int mb = blk & 1;
            const int b0 = mb * 128;
            const int i0 = ic * CHUNK;
            const int w = t >> 6, lane = t & 63, l15 = lane & 15, q = lane >> 4;

            floatx4 acc[2][10];
#pragma unroll
            for (int mt = 0; mt < 2; ++mt)
#pragma unroll
                for (int nt = 0; nt < 10; ++nt) acc[mt][nt] = (floatx4)(0.f);

            for (int round = 0; round < 4; ++round) {
                const int si0 = i0 + round * 4;          // 4 i = K-window 32
                if (round) __syncthreads();

                // ---- stage W: scale by c, split h/l; 640 (oe,i) items ----
#pragma unroll
                for (int r = 0; r < 3; ++r) {
                    int p = t + 256 * r;
                    if (p < 640) {
                        int oeL = p % 160;
                        int iL  = p / 160;
                        int o = oeL >> 4, e = oeL & 15;
                        const float* wp = W + (size_t)(si0 + iL) * WROW + o * 128 + e;
                        float cv = first ? 0.1f : cbuf[(si0 + iL) * O + o];
                        float tmp[8];
#pragma unroll
                        for (int d = 0; d < 8; ++d) tmp[d] = wp[d * 16] * cv;
                        short8 hv, lv; split8(tmp, hv, lv);
                        int off = oeL * LROW + iL * 8;
                        *(short8*)(sWh + off) = hv;
                        *(short8*)(sWl + off) = lv;
                    }
                }
                // ---- stage X (iter0: split fp32 x and persist to xh/xl) ----
#pragma unroll
                for (int r = 0; r < 2; ++r) {
                    int cgi = t + 256 * r;
                    int row = cgi >> 2, ch = cgi & 3;
                    size_t goff = (size_t)(b0 + row) * XROW + (size_t)si0 * 8 + ch * 8;
                    short8 hv, lv;
                    if (first) {
                        float tmp[8];
#pragma unroll
                        for (int d = 0; d < 8; ++d) tmp[d] = x[goff + d];
                        split8(tmp, hv, lv);
                        *(short8*)(xh + goff) = hv;
                        *(short8*)(xl + goff) = lv;
                    } else {
                        hv = *(const short8*)(xh + goff);
                        lv = *(const short8*)(xl + goff);
                    }
                    int off = row * LROW + ch * 8;
                    *(short8*)(sXh + off) = hv;
                    *(short8*)(sXl + off) = lv;
                }
                __syncthreads();

                // ---- one K=32 MFMA step, 3-term hi/lo ----
                short8 ah[2], al[2];
#pragma unroll
                for (int mt = 0; mt < 2; ++mt) {
                    int rm = w * 32 + mt * 16 + l15;
                    int off = rm * LROW + q * 8;
                    ah[mt] = *(const short8*)(sXh + off);
                    al[mt] = *(const short8*)(sXl + off);
                }
#pragma unroll
                for (int nt = 0; nt < 10; ++nt) {
                    int rn = nt * 16 + l15;
                    int off = rn * LROW + q * 8;
                    short8 bh = *(const short8*)(sWh + off);
                    short8 bv = *(const short8*)(sWl + off);
#pragma unroll
                    for (int mt = 0; mt < 2; ++mt) {
                        acc[mt][nt] = __builtin_amdgcn_mfma_f32_16x16x32_bf16(ah[mt], bh, acc[mt][nt], 0, 0, 0);
                        acc[mt][nt] = __builtin_amdgcn_mfma_f32_16x16x32_bf16(ah[mt], bv, acc[mt][nt], 0, 0, 0);
                        acc[mt][nt] = __builtin_amdgcn_mfma_f32_16x16x32_bf16(al[mt], bh, acc[mt][nt], 0, 0, 0);
                    }
                }
            }
            // ---- epilogue (C/D: col=lane&15, row=(lane>>4)*4+reg) ----
            float* base = sp + (size_t)ic * (B * OE);
#pragma unroll
            for (int mt = 0; mt < 2; ++mt) {
                int row0 = b0 + w * 32 + mt * 16 + q * 4;
#pragma unroll
                for (int nt = 0; nt < 10; ++nt) {
                    int col = nt * 16 + l15;
#pragma unroll
                    for (int reg = 0; reg < 4; ++reg)
                        base[(size_t)(row0 + reg) * OE + col] = acc[mt][nt][reg];
                }
            }
        }
        grid_bar(bcnt, bgen);

        // ================= VRED =================
        if (blk < 160) {
            float* dst = (iter == 2) ? out : vbuf;
            int g = blk * 256 + t;
            float s = 0.f;
#pragma unroll 8
            for (int icc = 0; icc < PSPLIT; ++icc) s += sp[(size_t)icc * (B * OE) + g];
            float ss = s * s;
            ss += __shfl_xor(ss, 1, 16);
            ss += __shfl_xor(ss, 2, 16);
            ss += __shfl_xor(ss, 4, 16);
            ss += __shfl_xor(ss, 8, 16);
            dst[g] = s * (sqrtf(ss) / (1.f + ss));   // squash
        }
        if (iter == 2) break;                        // out written; done
        grid_bar(bcnt, bgen);

        // ================= AGREE =================
        if (ni == 5) agree_phase<5>(x, W, vbuf, cbuf, bl, sBrow, iStart, t);
        else         agree_phase<4>(x, W, vbuf, cbuf, bl, sBrow, iStart, t);
        grid_bar(bcnt, bgen);
    }
}

// ---------------------------------------------------------------------------
extern "C" void kernel_launch(void* const* d_in, const int* in_sizes, int n_in,
                              void* d_out, int out_size, void* d_ws, size_t ws_size,
                              hipStream_t stream)
{
    const float* x = (const float*)d_in[0];   // [256,1152,8]
    const float* W = (const float*)d_in[1];   // [1152,10,8,16]
    float* out = (float*)d_out;               // [256,10,16,1] flat = 40960

    // ws: bar 256B | xh 4.72MB | xl 4.72MB | c 46KB | v 164KB | sp 11.8MB
    int* bar = (int*)d_ws;
    unsigned short* xh = (unsigned short*)((char*)d_ws + 256);
    unsigned short* xl = xh + (size_t)B * XROW;
    float* cbuf = (float*)(xl + (size_t)B * XROW);
    float* vbuf = cbuf + I_ * O;
    float* sp   = vbuf + B * OE;

    // zero the barrier slots (graph-capturable memset node)
    hipMemsetAsync(bar, 0, 256, stream);

    capsnet_fused<<<dim3(NBLK), dim3(256), 0, stream>>>(
        x, W, out, xh, xl, cbuf, vbuf, sp, bar);
}

// Round 6
// 571.409 us; speedup vs baseline: 1.1292x; 1.1292x over previous
//
#include <hip/hip_runtime.h>
#include <math.h>

#define B    256
#define I_   1152
#define O    10
#define DIN  8
#define OE   160          // O*DOUT
#define XROW 9216         // I*Din = K of the s-GEMM
#define WROW 1280         // O*Din*Dout
#define PSPLIT 72         // split-K partials (spart: 72 ic x 2 mb = 144 blocks)
#define CHUNK  16         // i per spart block
#define LROW   40         // padded LDS row stride (shorts), K-window 32 + 8 pad
#define NBLK   256        // grid size; 46KB LDS, 1 block/CU -> all co-resident
#define MASTER (NBLK - 1) // barrier master: idle during spart (>=144) & vred (>=160)
#define FSTR   32         // flag stride in ints = 128B (one L2 line per block)

typedef __attribute__((ext_vector_type(8))) short short8;
typedef __attribute__((ext_vector_type(4))) float floatx4;

__device__ __forceinline__ unsigned short f2bf(float f) {
    unsigned u = __builtin_bit_cast(unsigned, f);
    u += 0x7fffu + ((u >> 16) & 1u);          // RNE
    return (unsigned short)(u >> 16);
}
__device__ __forceinline__ float bf2f(unsigned short h) {
    unsigned u = ((unsigned)h) << 16;
    return __builtin_bit_cast(float, u);
}
__device__ __forceinline__ void split8(const float* s, short8& hv, short8& lv) {
#pragma unroll
    for (int d = 0; d < 8; ++d) {
        unsigned short h = f2bf(s[d]);
        hv[d] = (short)h;
        lv[d] = (short)f2bf(s[d] - bf2f(h));
    }
}

// ---------------------------------------------------------------------------
// Distributed grid barrier (no cooperative launch, no contended RMW).
//  arrive : block's t0 RELEASE-stores phase into its own 128B flag line.
//  gather : MASTER block's 256 threads poll one flag each (parallel), then
//           publish phase to 8 replicated gen lines (<=32 pollers per line).
//  wait   : each block's t0 polls gen[blk&7]; t0 __threadfence() = cache-wide
//           L1 invalidate for the whole CU (R5-proven visibility machinery).
// Monotonic phase values (1..7) -> no reset race. All 256 blocks co-resident
// by construction (256 blocks / 256 CUs), so spinning cannot deadlock.
// ---------------------------------------------------------------------------
__device__ __forceinline__ void grid_bar(int* flags, int* gen, int ph,
                                         int blk, int t) {
    __syncthreads();
    if (t == 0) {
        __threadfence();   // release: drain my block's writes past L2/LLC
        __hip_atomic_store(flags + blk * FSTR, ph, __ATOMIC_RELEASE,
                           __HIP_MEMORY_SCOPE_AGENT);
    }
    if (blk == MASTER) {
        while (__hip_atomic_load(flags + t * FSTR, __ATOMIC_RELAXED,
                                 __HIP_MEMORY_SCOPE_AGENT) < ph)
            __builtin_amdgcn_s_sleep(1);
        __syncthreads();
        if (t < 8)
            __hip_atomic_store(gen + t * FSTR, ph, __ATOMIC_RELEASE,
                               __HIP_MEMORY_SCOPE_AGENT);
    } else if (t == 0) {
        while (__hip_atomic_load(gen + (blk & 7) * FSTR, __ATOMIC_RELAXED,
                                 __HIP_MEMORY_SCOPE_AGENT) < ph)
            __builtin_amdgcn_s_sleep(1);
    }
    if (t == 0) __threadfence();   // acquire: invalidate stale L1 (CU-wide)
    __syncthreads();
}

// ---------------------------------------------------------------------------
// AGREE phase: block owns NI i's. Thread t<160 owns column oe=t.
//   G[i,d,oe] = sum_b x[b,i,d]*v[b,oe]  -- x via wave-uniform s_load, v one
//   coalesced vector load per b; zero LDS in the hot loop.
//   agree[i,o] = (1/B) sum_{d,e} W[i,o,d,e]*G[i,d,oe]; b+=agree; c=softmax(b)
// ---------------------------------------------------------------------------
template<int NI>
__device__ __forceinline__ void agree_phase(
    const float* __restrict__ x, const float* __restrict__ W,
    const float* __restrict__ v, float* __restrict__ cbuf,
    float* bl, float (*brow)[16], int iStart, int t)
{
    const int o = t >> 4, e = t & 15;
    if (t < OE) {
        float acc[NI][8];
#pragma unroll
        for (int ii = 0; ii < NI; ++ii)
#pragma unroll
            for (int d = 0; d < 8; ++d) acc[ii][d] = 0.f;

#pragma unroll 4
        for (int b = 0; b < B; ++b) {
            float vv = v[b * OE + t];                              // coalesced
            const float* xr = x + (size_t)b * XROW + iStart * DIN; // uniform
#pragma unroll
            for (int ii = 0; ii < NI; ++ii)
#pragma unroll
                for (int d = 0; d < 8; ++d)
                    acc[ii][d] = fmaf(xr[ii * 8 + d], vv, acc[ii][d]);
        }
#pragma unroll
        for (int ii = 0; ii < NI; ++ii) {
            const float* wr = W + (size_t)(iStart + ii) * WROW + o * 128 + e;
            float p = 0.f;
#pragma unroll
            for (int d = 0; d < 8; ++d) p = fmaf(wr[d * 16], acc[ii][d], p);
            p += __shfl_xor(p, 8, 16);
            p += __shfl_xor(p, 4, 16);
            p += __shfl_xor(p, 2, 16);
            p += __shfl_xor(p, 1, 16);
            bl[ii] += p * (1.f / 256.f);       // uniform within 16-lane group
            if (e == 0) brow[ii][o] = bl[ii];
        }
    }
    __syncthreads();
    if (t < NI) {
        float m = brow[t][0];
#pragma unroll
        for (int oo = 1; oo < O; ++oo) m = fmaxf(m, brow[t][oo]);
        float ex[O], sum = 0.f;
#pragma unroll
        for (int oo = 0; oo < O; ++oo) { ex[oo] = __expf(brow[t][oo] - m); sum += ex[oo]; }
        float inv = 1.f / sum;
#pragma unroll
        for (int oo = 0; oo < O; ++oo) cbuf[(iStart + t) * O + oo] = ex[oo] * inv;
    }
}

// ---------------------------------------------------------------------------
// Fully-fused CapsNet routing: one plain kernel, 256 blocks x 256 threads,
// distributed grid barriers between phases.
//   per iter: SPART (144 blocks, MFMA bf16 hi/lo split-K GEMM, K-window 32)
//             -> bar -> VRED (160 blocks, sum 72 partials + squash)
//             -> bar -> AGREE (all 256 blocks, 4-5 i each) -> bar
// iter-0 spart also performs the x fp32->bf16 h/l split (its x-tiles exactly
// partition x).
// ---------------------------------------------------------------------------
__global__ void __launch_bounds__(256)
capsnet_fused(const float* __restrict__ x, const float* __restrict__ W,
              float* __restrict__ out,
              unsigned short* __restrict__ xh, unsigned short* __restrict__ xl,
              float* __restrict__ cbuf, float* __restrict__ vbuf,
              float* __restrict__ sp, int* __restrict__ bar)
{
    __shared__ unsigned short sWh[OE * LROW], sWl[OE * LROW];     // 12.5 KB x2
    __shared__ unsigned short sXh[128 * LROW], sXl[128 * LROW];   // 10 KB x2
    __shared__ float sBrow[5][16];

    int* flags = bar;                  // NBLK * FSTR ints (32 KB)
    int* gen   = bar + NBLK * FSTR;    // 8 * FSTR ints (1 KB)

    const int blk = blockIdx.x;
    const int t   = threadIdx.x;
    int ph = 0;

    float bl[5] = {0.f, 0.f, 0.f, 0.f, 0.f};   // routing logits (registers)
    int iStart, ni;
    if (blk < 128) { ni = 5; iStart = blk * 5; }
    else           { ni = 4; iStart = 640 + (blk - 128) * 4; }

    for (int iter = 0; iter < 3; ++iter) {
        const int first = (iter == 0);

        // ================= SPART =================
        if (blk < 144) {
            const int ic = blk >> 1;
            const int mb = blk & 1;
            const int b0 = mb * 128;
            const int i0 = ic * CHUNK;
            const int w = t >> 6, lane = t & 63, l15 = lane & 15, q = lane >> 4;

            floatx4 acc[2][10];
#pragma unroll
            for (int mt = 0; mt < 2; ++mt)
#pragma unroll
                for (int nt = 0; nt < 10; ++nt) acc[mt][nt] = (floatx4)(0.f);

            for (int round = 0; round < 4; ++round) {
                const int si0 = i0 + round * 4;          // 4 i = K-window 32
                if (round) __syncthreads();

                // ---- stage W: scale by c, split h/l; 640 (oe,i) items ----
#pragma unroll
                for (int r = 0; r < 3; ++r) {
                    int p = t + 256 * r;
                    if (p < 640) {
                        int oeL = p % 160;
                        int iL  = p / 160;
                        int o = oeL >> 4, e = oeL & 15;
                        const float* wp = W + (size_t)(si0 + iL) * WROW + o * 128 + e;
                        float cv = first ? 0.1f : cbuf[(si0 + iL) * O + o];
                        float tmp[8];
#pragma unroll
                        for (int d = 0; d < 8; ++d) tmp[d] = wp[d * 16] * cv;
                        short8 hv, lv; split8(tmp, hv, lv);
                        int off = oeL * LROW + iL * 8;
                        *(short8*)(sWh + off) = hv;
                        *(short8*)(sWl + off) = lv;
                    }
                }
                // ---- stage X (iter0: split fp32 x and persist to xh/xl) ----
#pragma unroll
                for (int r = 0; r < 2; ++r) {
                    int cgi = t + 256 * r;
                    int row = cgi >> 2, ch = cgi & 3;
                    size_t goff = (size_t)(b0 + row) * XROW + (size_t)si0 * 8 + ch * 8;
                    short8 hv, lv;
                    if (first) {
                        float tmp[8];
#pragma unroll
                        for (int d = 0; d < 8; ++d) tmp[d] = x[goff + d];
                        split8(tmp, hv, lv);
                        *(short8*)(xh + goff) = hv;
                        *(short8*)(xl + goff) = lv;
                    } else {
                        hv = *(const short8*)(xh + goff);
                        lv = *(const short8*)(xl + goff);
                    }
                    int off = row * LROW + ch * 8;
                    *(short8*)(sXh + off) = hv;
                    *(short8*)(sXl + off) = lv;
                }
                __syncthreads();

                // ---- one K=32 MFMA step, 3-term hi/lo ----
                short8 ah[2], al[2];
#pragma unroll
                for (int mt = 0; mt < 2; ++mt) {
                    int rm = w * 32 + mt * 16 + l15;
                    int off = rm * LROW + q * 8;
                    ah[mt] = *(const short8*)(sXh + off);
                    al[mt] = *(const short8*)(sXl + off);
                }
#pragma unroll
                for (int nt = 0; nt < 10; ++nt) {
                    int rn = nt * 16 + l15;
                    int off = rn * LROW + q * 8;
                    short8 bh = *(const short8*)(sWh + off);
                    short8 bv = *(const short8*)(sWl + off);
#pragma unroll
                    for (int mt = 0; mt < 2; ++mt) {
                        acc[mt][nt] = __builtin_amdgcn_mfma_f32_16x16x32_bf16(ah[mt], bh, acc[mt][nt], 0, 0, 0);
                        acc[mt][nt] = __builtin_amdgcn_mfma_f32_16x16x32_bf16(ah[mt], bv, acc[mt][nt], 0, 0, 0);
                        acc[mt][nt] = __builtin_amdgcn_mfma_f32_16x16x32_bf16(al[mt], bh, acc[mt][nt], 0, 0, 0);
                    }
                }
            }
            // ---- epilogue (C/D: col=lane&15, row=(lane>>4)*4+reg) ----
            float* base = sp + (size_t)ic * (B * OE);
#pragma unroll
            for (int mt = 0; mt < 2; ++mt) {
                int row0 = b0 + w * 32 + mt * 16 + q * 4;
#pragma unroll
                for (int nt = 0; nt < 10; ++nt) {
                    int col = nt * 16 + l15;
#pragma unroll
                    for (int reg = 0; reg < 4; ++reg)
                        base[(size_t)(row0 + reg) * OE + col] = acc[mt][nt][reg];
                }
            }
        }
        grid_bar(flags, gen, ++ph, blk, t);

        // ================= VRED =================
        if (blk < 160) {
            float* dst = (iter == 2) ? out : vbuf;
            int g = blk * 256 + t;
            float s = 0.f;
#pragma unroll 8
            for (int icc = 0; icc < PSPLIT; ++icc) s += sp[(size_t)icc * (B * OE) + g];
            float ss = s * s;
            ss += __shfl_xor(ss, 1, 16);
            ss += __shfl_xor(ss, 2, 16);
            ss += __shfl_xor(ss, 4, 16);
            ss += __shfl_xor(ss, 8, 16);
            dst[g] = s * (sqrtf(ss) / (1.f + ss));   // squash
        }
        if (iter == 2) break;                        // out written; done
        grid_bar(flags, gen, ++ph, blk, t);

        // ================= AGREE =================
        if (ni == 5) agree_phase<5>(x, W, vbuf, cbuf, bl, sBrow, iStart, t);
        else         agree_phase<4>(x, W, vbuf, cbuf, bl, sBrow, iStart, t);
        grid_bar(flags, gen, ++ph, blk, t);
    }
}

// ---------------------------------------------------------------------------
extern "C" void kernel_launch(void* const* d_in, const int* in_sizes, int n_in,
                              void* d_out, int out_size, void* d_ws, size_t ws_size,
                              hipStream_t stream)
{
    const float* x = (const float*)d_in[0];   // [256,1152,8]
    const float* W = (const float*)d_in[1];   // [1152,10,8,16]
    float* out = (float*)d_out;               // [256,10,16,1] flat = 40960

    // ws: bar 40KB | xh 4.72MB | xl 4.72MB | c 46KB | v 164KB | sp 11.8MB
    const size_t BAR_BYTES = (size_t)(NBLK + 8) * FSTR * sizeof(int); // 33.8KB
    int* bar = (int*)d_ws;
    unsigned short* xh = (unsigned short*)((char*)d_ws + 40960);
    unsigned short* xl = xh + (size_t)B * XROW;
    float* cbuf = (float*)(xl + (size_t)B * XROW);
    float* vbuf = cbuf + I_ * O;
    float* sp   = vbuf + B * OE;

    // zero the barrier flags (graph-capturable memset node)
    hipMemsetAsync(bar, 0, BAR_BYTES, stream);

    capsnet_fused<<<dim3(NBLK), dim3(256), 0, stream>>>(
        x, W, out, xh, xl, cbuf, vbuf, sp, bar);
}

// Round 7
// 345.731 us; speedup vs baseline: 1.8663x; 1.6528x over previous
//
#include <hip/hip_runtime.h>
#include <math.h>

#define B    256
#define I_   1152
#define O    10
#define DIN  8
#define OE   160          // O*DOUT
#define XROW 9216         // I*Din = K of the s-GEMM
#define WROW 1280         // O*Din*Dout
#define CHUNK  8          // i per spart block (144 ic x 2 mb = 288 blocks)
#define LROW   40         // padded LDS row stride (shorts): K-window 32 + 8 pad
#define NI     3          // i per agree block (384 blocks)

typedef __attribute__((ext_vector_type(8))) short short8;
typedef __attribute__((ext_vector_type(4))) float floatx4;

__device__ __forceinline__ unsigned short f2bf(float f) {
    unsigned u = __builtin_bit_cast(unsigned, f);
    u += 0x7fffu + ((u >> 16) & 1u);          // RNE
    return (unsigned short)(u >> 16);
}
__device__ __forceinline__ float bf2f(unsigned short h) {
    unsigned u = ((unsigned)h) << 16;
    return __builtin_bit_cast(float, u);
}
__device__ __forceinline__ void split8(const float* s, short8& hv, short8& lv) {
#pragma unroll
    for (int d = 0; d < 8; ++d) {
        unsigned short h = f2bf(s[d]);
        hv[d] = (short)h;
        lv[d] = (short)f2bf(s[d] - bf2f(h));
    }
}

// ---------------------------------------------------------------------------
// SPART: MFMA bf16 hi/lo GEMM, accumulating straight into s[256,160] with
// HW fp32 atomics (no split-K partial buffer, no vred kernel).
// grid 288 = 144 i-chunks x 2 b-halves; 2 rounds of K-window 32 (4 i).
// iter0 (first=1) also splits fp32 x -> bf16 xh/xl and persists them
// (block tiles exactly partition x). R6-verified MFMA/staging logic.
// ---------------------------------------------------------------------------
__global__ void __launch_bounds__(256)
spart_kernel(const float* __restrict__ x, const float* __restrict__ W,
             const float* __restrict__ cbuf,
             unsigned short* __restrict__ xh, unsigned short* __restrict__ xl,
             float* __restrict__ s, int first)
{
    __shared__ unsigned short sWh[OE * LROW], sWl[OE * LROW];     // 12.5 KB x2
    __shared__ unsigned short sXh[128 * LROW], sXl[128 * LROW];   // 10 KB x2

    const int blk = blockIdx.x;
    const int ic = blk >> 1;
    const int mb = blk & 1;
    const int b0 = mb * 128;
    const int i0 = ic * CHUNK;
    const int t = threadIdx.x;
    const int w = t >> 6, lane = t & 63, l15 = lane & 15, q = lane >> 4;

    floatx4 acc[2][10];
#pragma unroll
    for (int mt = 0; mt < 2; ++mt)
#pragma unroll
        for (int nt = 0; nt < 10; ++nt) acc[mt][nt] = (floatx4)(0.f);

    for (int round = 0; round < CHUNK / 4; ++round) {
        const int si0 = i0 + round * 4;              // 4 i = K-window 32
        if (round) __syncthreads();

        // ---- stage W: scale by c, split h/l; 640 (oe,i) items ----
#pragma unroll
        for (int r = 0; r < 3; ++r) {
            int p = t + 256 * r;
            if (p < 640) {
                int oeL = p % 160;
                int iL  = p / 160;
                int o = oeL >> 4, e = oeL & 15;
                const float* wp = W + (size_t)(si0 + iL) * WROW + o * 128 + e;
                float cv = first ? 0.1f : cbuf[(si0 + iL) * O + o];
                float tmp[8];
#pragma unroll
                for (int d = 0; d < 8; ++d) tmp[d] = wp[d * 16] * cv;
                short8 hv, lv; split8(tmp, hv, lv);
                int off = oeL * LROW + iL * 8;
                *(short8*)(sWh + off) = hv;
                *(short8*)(sWl + off) = lv;
            }
        }
        // ---- stage X (iter0: split fp32 x and persist to xh/xl) ----
#pragma unroll
        for (int r = 0; r < 2; ++r) {
            int cgi = t + 256 * r;
            int row = cgi >> 2, ch = cgi & 3;
            size_t goff = (size_t)(b0 + row) * XROW + (size_t)si0 * 8 + ch * 8;
            short8 hv, lv;
            if (first) {
                float tmp[8];
#pragma unroll
                for (int d = 0; d < 8; ++d) tmp[d] = x[goff + d];
                split8(tmp, hv, lv);
                *(short8*)(xh + goff) = hv;
                *(short8*)(xl + goff) = lv;
            } else {
                hv = *(const short8*)(xh + goff);
                lv = *(const short8*)(xl + goff);
            }
            int off = row * LROW + ch * 8;
            *(short8*)(sXh + off) = hv;
            *(short8*)(sXl + off) = lv;
        }
        __syncthreads();

        // ---- one K=32 MFMA step, 3-term hi/lo ----
        short8 ah[2], al[2];
#pragma unroll
        for (int mt = 0; mt < 2; ++mt) {
            int rm = w * 32 + mt * 16 + l15;
            int off = rm * LROW + q * 8;
            ah[mt] = *(const short8*)(sXh + off);
            al[mt] = *(const short8*)(sXl + off);
        }
#pragma unroll
        for (int nt = 0; nt < 10; ++nt) {
            int rn = nt * 16 + l15;
            int off = rn * LROW + q * 8;
            short8 bh = *(const short8*)(sWh + off);
            short8 bv = *(const short8*)(sWl + off);
#pragma unroll
            for (int mt = 0; mt < 2; ++mt) {
                acc[mt][nt] = __builtin_amdgcn_mfma_f32_16x16x32_bf16(ah[mt], bh, acc[mt][nt], 0, 0, 0);
                acc[mt][nt] = __builtin_amdgcn_mfma_f32_16x16x32_bf16(ah[mt], bv, acc[mt][nt], 0, 0, 0);
                acc[mt][nt] = __builtin_amdgcn_mfma_f32_16x16x32_bf16(al[mt], bh, acc[mt][nt], 0, 0, 0);
            }
        }
    }

    // ---- epilogue: atomic-accumulate into s (C/D: col=lane&15, row=quad*4+reg)
#pragma unroll
    for (int mt = 0; mt < 2; ++mt) {
        int row0 = b0 + w * 32 + mt * 16 + q * 4;
#pragma unroll
        for (int nt = 0; nt < 10; ++nt) {
            int col = nt * 16 + l15;
#pragma unroll
            for (int reg = 0; reg < 4; ++reg)
                unsafeAtomicAdd(&s[(size_t)(row0 + reg) * OE + col],
                                acc[mt][nt][reg]);
        }
    }
}

// ---------------------------------------------------------------------------
// AGREE: squash fused on-the-fly (reads raw sums s, never materializes v).
// Block owns NI=3 i's; thread t<160 owns column oe=t (o=t>>4, e=t&15).
//   v[b,t] = s[b,t]*sqrt(ss)/(1+ss), ss via 16-lane shfl reduction
//   G[i,d] += x[b,i,d]*v[b,t]  (x wave-uniform -> scalar loads)
//   agree = (1/B) sum_{d,e} W*G; blog += agree; cbuf = softmax(blog)
// ---------------------------------------------------------------------------
template<int FIRST>
__global__ void __launch_bounds__(256)
agree_kernel(const float* __restrict__ x, const float* __restrict__ W,
             const float* __restrict__ s, float* __restrict__ blog,
             float* __restrict__ cbuf)
{
    const int blk = blockIdx.x;
    const int iStart = blk * NI;
    const int t = threadIdx.x;
    __shared__ float brow[NI][16];

    if (t < OE) {
        const int o = t >> 4, e = t & 15;
        float acc[NI][8];
#pragma unroll
        for (int ii = 0; ii < NI; ++ii)
#pragma unroll
            for (int d = 0; d < 8; ++d) acc[ii][d] = 0.f;

#pragma unroll 4
        for (int b = 0; b < B; ++b) {
            float sv = s[b * OE + t];                  // coalesced
            float ss = sv * sv;
            ss += __shfl_xor(ss, 1, 16);
            ss += __shfl_xor(ss, 2, 16);
            ss += __shfl_xor(ss, 4, 16);
            ss += __shfl_xor(ss, 8, 16);
            float vv = sv * (sqrtf(ss) / (1.f + ss));  // v[b,t] on the fly
            const float* xr = x + (size_t)b * XROW + iStart * DIN;  // uniform
#pragma unroll
            for (int ii = 0; ii < NI; ++ii)
#pragma unroll
                for (int d = 0; d < 8; ++d)
                    acc[ii][d] = fmaf(xr[ii * 8 + d], vv, acc[ii][d]);
        }
#pragma unroll
        for (int ii = 0; ii < NI; ++ii) {
            const float* wr = W + (size_t)(iStart + ii) * WROW + o * 128 + e;
            float p = 0.f;
#pragma unroll
            for (int d = 0; d < 8; ++d) p = fmaf(wr[d * 16], acc[ii][d], p);
            p += __shfl_xor(p, 8, 16);
            p += __shfl_xor(p, 4, 16);
            p += __shfl_xor(p, 2, 16);
            p += __shfl_xor(p, 1, 16);
            if (e == 0) {
                float bo = (FIRST ? 0.f : blog[(iStart + ii) * O + o])
                           + p * (1.f / 256.f);
                blog[(iStart + ii) * O + o] = bo;
                brow[ii][o] = bo;
            }
        }
    }
    __syncthreads();
    if (t < NI) {
        float m = brow[t][0];
#pragma unroll
        for (int oo = 1; oo < O; ++oo) m = fmaxf(m, brow[t][oo]);
        float ex[O], sum = 0.f;
#pragma unroll
        for (int oo = 0; oo < O; ++oo) { ex[oo] = __expf(brow[t][oo] - m); sum += ex[oo]; }
        float inv = 1.f / sum;
#pragma unroll
        for (int oo = 0; oo < O; ++oo) cbuf[(iStart + t) * O + oo] = ex[oo] * inv;
    }
}

// ---------------------------------------------------------------------------
// VSQUASH: final squash of the iter-3 sums into d_out.
// ---------------------------------------------------------------------------
__global__ void __launch_bounds__(256)
vsquash_kernel(const float* __restrict__ s, float* __restrict__ out)
{
    int g = blockIdx.x * 256 + threadIdx.x;
    float sv = s[g];
    float ss = sv * sv;
    ss += __shfl_xor(ss, 1, 16);
    ss += __shfl_xor(ss, 2, 16);
    ss += __shfl_xor(ss, 4, 16);
    ss += __shfl_xor(ss, 8, 16);
    out[g] = sv * (sqrtf(ss) / (1.f + ss));
}

// ---------------------------------------------------------------------------
extern "C" void kernel_launch(void* const* d_in, const int* in_sizes, int n_in,
                              void* d_out, int out_size, void* d_ws, size_t ws_size,
                              hipStream_t stream)
{
    const float* x = (const float*)d_in[0];   // [256,1152,8]
    const float* W = (const float*)d_in[1];   // [1152,10,8,16]
    float* out = (float*)d_out;               // [256,10,16,1] flat = 40960

    // ws: s0|s1|s2 (3 x 160KB, memset 0) | blog 46KB | c 46KB | xh | xl
    float* s0   = (float*)d_ws;
    float* s1   = s0 + B * OE;
    float* s2   = s1 + B * OE;
    float* blog = s2 + B * OE;
    float* cbuf = blog + I_ * O;
    unsigned short* xh = (unsigned short*)(cbuf + I_ * O);
    unsigned short* xl = xh + (size_t)B * XROW;

    // zero the three atomic accumulators (one graph-capturable memset node)
    hipMemsetAsync(s0, 0, 3 * B * OE * sizeof(float), stream);

    // ---- iter 1 (c uniform 0.1 via first; also splits x -> xh/xl) ----
    spart_kernel<<<288, 256, 0, stream>>>(x, W, cbuf, xh, xl, s0, 1);
    agree_kernel<1><<<I_ / NI, 256, 0, stream>>>(x, W, s0, blog, cbuf);
    // ---- iter 2 ----
    spart_kernel<<<288, 256, 0, stream>>>(x, W, cbuf, xh, xl, s1, 0);
    agree_kernel<0><<<I_ / NI, 256, 0, stream>>>(x, W, s1, blog, cbuf);
    // ---- iter 3 ----
    spart_kernel<<<288, 256, 0, stream>>>(x, W, cbuf, xh, xl, s2, 0);
    vsquash_kernel<<<160, 256, 0, stream>>>(s2, out);
}

// Round 8
// 233.463 us; speedup vs baseline: 2.7638x; 1.4809x over previous
//
#include <hip/hip_runtime.h>
#include <math.h>

#define B    256
#define I_   1152
#define O    10
#define DIN  8
#define OE   160          // O*DOUT
#define XROW 9216         // I*Din = K of the s-GEMM
#define WROW 1280         // O*Din*Dout
#define CHUNK  8          // i per spart block (144 ic x 2 mb = 288 blocks)
#define LROW   40         // padded LDS row stride (shorts): K-window 32 + 8 pad
#define NI     4          // i per agree block (288 blocks)

typedef __attribute__((ext_vector_type(8))) short short8;
typedef __attribute__((ext_vector_type(4))) float floatx4;

__device__ __forceinline__ unsigned short f2bf(float f) {
    unsigned u = __builtin_bit_cast(unsigned, f);
    u += 0x7fffu + ((u >> 16) & 1u);          // RNE
    return (unsigned short)(u >> 16);
}
__device__ __forceinline__ float bf2f(unsigned short h) {
    unsigned u = ((unsigned)h) << 16;
    return __builtin_bit_cast(float, u);
}
__device__ __forceinline__ void split8(const float* s, short8& hv, short8& lv) {
#pragma unroll
    for (int d = 0; d < 8; ++d) {
        unsigned short h = f2bf(s[d]);
        hv[d] = (short)h;
        lv[d] = (short)f2bf(s[d] - bf2f(h));
    }
}

// ---------------------------------------------------------------------------
// SPART: MFMA bf16 hi/lo GEMM, accumulating straight into s[256,160] with
// HW fp32 atomics (no split-K partial buffer). R7-proven.
// grid 288 = 144 i-chunks x 2 b-halves; 2 rounds of K-window 32 (4 i).
// iter0 (first=1) also splits fp32 x -> bf16 xh/xl and persists them.
// ---------------------------------------------------------------------------
__global__ void __launch_bounds__(256)
spart_kernel(const float* __restrict__ x, const float* __restrict__ W,
             const float* __restrict__ cbuf,
             unsigned short* __restrict__ xh, unsigned short* __restrict__ xl,
             float* __restrict__ s, int first)
{
    __shared__ unsigned short sWh[OE * LROW], sWl[OE * LROW];     // 12.5 KB x2
    __shared__ unsigned short sXh[128 * LROW], sXl[128 * LROW];   // 10 KB x2

    const int blk = blockIdx.x;
    const int ic = blk >> 1;
    const int mb = blk & 1;
    const int b0 = mb * 128;
    const int i0 = ic * CHUNK;
    const int t = threadIdx.x;
    const int w = t >> 6, lane = t & 63, l15 = lane & 15, q = lane >> 4;

    floatx4 acc[2][10];
#pragma unroll
    for (int mt = 0; mt < 2; ++mt)
#pragma unroll
        for (int nt = 0; nt < 10; ++nt) acc[mt][nt] = (floatx4)(0.f);

    for (int round = 0; round < CHUNK / 4; ++round) {
        const int si0 = i0 + round * 4;              // 4 i = K-window 32
        if (round) __syncthreads();

        // ---- stage W: scale by c, split h/l; 640 (oe,i) items ----
#pragma unroll
        for (int r = 0; r < 3; ++r) {
            int p = t + 256 * r;
            if (p < 640) {
                int oeL = p % 160;
                int iL  = p / 160;
                int o = oeL >> 4, e = oeL & 15;
                const float* wp = W + (size_t)(si0 + iL) * WROW + o * 128 + e;
                float cv = first ? 0.1f : cbuf[(si0 + iL) * O + o];
                float tmp[8];
#pragma unroll
                for (int d = 0; d < 8; ++d) tmp[d] = wp[d * 16] * cv;
                short8 hv, lv; split8(tmp, hv, lv);
                int off = oeL * LROW + iL * 8;
                *(short8*)(sWh + off) = hv;
                *(short8*)(sWl + off) = lv;
            }
        }
        // ---- stage X (iter0: split fp32 x and persist to xh/xl) ----
#pragma unroll
        for (int r = 0; r < 2; ++r) {
            int cgi = t + 256 * r;
            int row = cgi >> 2, ch = cgi & 3;
            size_t goff = (size_t)(b0 + row) * XROW + (size_t)si0 * 8 + ch * 8;
            short8 hv, lv;
            if (first) {
                float tmp[8];
#pragma unroll
                for (int d = 0; d < 8; ++d) tmp[d] = x[goff + d];
                split8(tmp, hv, lv);
                *(short8*)(xh + goff) = hv;
                *(short8*)(xl + goff) = lv;
            } else {
                hv = *(const short8*)(xh + goff);
                lv = *(const short8*)(xl + goff);
            }
            int off = row * LROW + ch * 8;
            *(short8*)(sXh + off) = hv;
            *(short8*)(sXl + off) = lv;
        }
        __syncthreads();

        // ---- one K=32 MFMA step, 3-term hi/lo ----
        short8 ah[2], al[2];
#pragma unroll
        for (int mt = 0; mt < 2; ++mt) {
            int rm = w * 32 + mt * 16 + l15;
            int off = rm * LROW + q * 8;
            ah[mt] = *(const short8*)(sXh + off);
            al[mt] = *(const short8*)(sXl + off);
        }
#pragma unroll
        for (int nt = 0; nt < 10; ++nt) {
            int rn = nt * 16 + l15;
            int off = rn * LROW + q * 8;
            short8 bh = *(const short8*)(sWh + off);
            short8 bv = *(const short8*)(sWl + off);
#pragma unroll
            for (int mt = 0; mt < 2; ++mt) {
                acc[mt][nt] = __builtin_amdgcn_mfma_f32_16x16x32_bf16(ah[mt], bh, acc[mt][nt], 0, 0, 0);
                acc[mt][nt] = __builtin_amdgcn_mfma_f32_16x16x32_bf16(ah[mt], bv, acc[mt][nt], 0, 0, 0);
                acc[mt][nt] = __builtin_amdgcn_mfma_f32_16x16x32_bf16(al[mt], bh, acc[mt][nt], 0, 0, 0);
            }
        }
    }

    // ---- epilogue: atomic-accumulate into s (C/D: col=lane&15, row=quad*4+reg)
#pragma unroll
    for (int mt = 0; mt < 2; ++mt) {
        int row0 = b0 + w * 32 + mt * 16 + q * 4;
#pragma unroll
        for (int nt = 0; nt < 10; ++nt) {
            int col = nt * 16 + l15;
#pragma unroll
            for (int reg = 0; reg < 4; ++reg)
                unsafeAtomicAdd(&s[(size_t)(row0 + reg) * OE + col],
                                acc[mt][nt][reg]);
        }
    }
}

// ---------------------------------------------------------------------------
// VSQUASH: squash raw sums s -> v (or final output). 160 blocks x 256 thr.
// ---------------------------------------------------------------------------
__global__ void __launch_bounds__(256)
vsquash_kernel(const float* __restrict__ s, float* __restrict__ dst)
{
    int g = blockIdx.x * 256 + threadIdx.x;
    float sv = s[g];
    float ss = sv * sv;
    ss += __shfl_xor(ss, 1, 16);
    ss += __shfl_xor(ss, 2, 16);
    ss += __shfl_xor(ss, 4, 16);
    ss += __shfl_xor(ss, 8, 16);
    dst[g] = sv * (sqrtf(ss) / (1.f + ss));
}

// ---------------------------------------------------------------------------
// AGREE v2: consumes precomputed v — hot loop is load + FMA only (no shfl,
// no sqrt), unroll 8 keeps 8 v-loads in flight. Block owns NI=4 i's;
// thread t<160 owns column oe=t. x loads wave-uniform -> scalar pipe.
//   G[i,d] = sum_b x[b,i,d]*v[b,t]; agree=(1/B) sum W*G; blog+=; c=softmax
// ---------------------------------------------------------------------------
template<int FIRST>
__global__ void __launch_bounds__(256)
agree_kernel(const float* __restrict__ x, const float* __restrict__ W,
             const float* __restrict__ v, float* __restrict__ blog,
             float* __restrict__ cbuf)
{
    const int iStart = blockIdx.x * NI;
    const int t = threadIdx.x;
    __shared__ float brow[NI][16];

    if (t < OE) {
        const int o = t >> 4, e = t & 15;
        float acc[NI][8];
#pragma unroll
        for (int ii = 0; ii < NI; ++ii)
#pragma unroll
            for (int d = 0; d < 8; ++d) acc[ii][d] = 0.f;

        const float* vp = v + t;
        const float* xp = x + (size_t)iStart * DIN;
#pragma unroll 8
        for (int b = 0; b < B; ++b) {
            float vv = vp[b * OE];                     // coalesced, independent
            const float* xr = xp + (size_t)b * XROW;   // wave-uniform
#pragma unroll
            for (int ii = 0; ii < NI; ++ii)
#pragma unroll
                for (int d = 0; d < 8; ++d)
                    acc[ii][d] = fmaf(xr[ii * 8 + d], vv, acc[ii][d]);
        }
#pragma unroll
        for (int ii = 0; ii < NI; ++ii) {
            const float* wr = W + (size_t)(iStart + ii) * WROW + o * 128 + e;
            float p = 0.f;
#pragma unroll
            for (int d = 0; d < 8; ++d) p = fmaf(wr[d * 16], acc[ii][d], p);
            p += __shfl_xor(p, 8, 16);
            p += __shfl_xor(p, 4, 16);
            p += __shfl_xor(p, 2, 16);
            p += __shfl_xor(p, 1, 16);
            if (e == 0) {
                float bo = (FIRST ? 0.f : blog[(iStart + ii) * O + o])
                           + p * (1.f / 256.f);
                blog[(iStart + ii) * O + o] = bo;
                brow[ii][o] = bo;
            }
        }
    }
    __syncthreads();
    if (t < NI) {
        float m = brow[t][0];
#pragma unroll
        for (int oo = 1; oo < O; ++oo) m = fmaxf(m, brow[t][oo]);
        float ex[O], sum = 0.f;
#pragma unroll
        for (int oo = 0; oo < O; ++oo) { ex[oo] = __expf(brow[t][oo] - m); sum += ex[oo]; }
        float inv = 1.f / sum;
#pragma unroll
        for (int oo = 0; oo < O; ++oo) cbuf[(iStart + t) * O + oo] = ex[oo] * inv;
    }
}

// ---------------------------------------------------------------------------
extern "C" void kernel_launch(void* const* d_in, const int* in_sizes, int n_in,
                              void* d_out, int out_size, void* d_ws, size_t ws_size,
                              hipStream_t stream)
{
    const float* x = (const float*)d_in[0];   // [256,1152,8]
    const float* W = (const float*)d_in[1];   // [1152,10,8,16]
    float* out = (float*)d_out;               // [256,10,16,1] flat = 40960

    // ws: s0|s1|s2 (3 x 160KB, memset 0) | vbuf | blog | c | xh | xl
    float* s0   = (float*)d_ws;
    float* s1   = s0 + B * OE;
    float* s2   = s1 + B * OE;
    float* vbuf = s2 + B * OE;
    float* blog = vbuf + B * OE;
    float* cbuf = blog + I_ * O;
    unsigned short* xh = (unsigned short*)(cbuf + I_ * O);
    unsigned short* xl = xh + (size_t)B * XROW;

    // zero the three atomic accumulators (one graph-capturable memset node)
    hipMemsetAsync(s0, 0, 3 * B * OE * sizeof(float), stream);

    // ---- iter 1 (c uniform 0.1 via first; also splits x -> xh/xl) ----
    spart_kernel<<<288, 256, 0, stream>>>(x, W, cbuf, xh, xl, s0, 1);
    vsquash_kernel<<<160, 256, 0, stream>>>(s0, vbuf);
    agree_kernel<1><<<I_ / NI, 256, 0, stream>>>(x, W, vbuf, blog, cbuf);
    // ---- iter 2 ----
    spart_kernel<<<288, 256, 0, stream>>>(x, W, cbuf, xh, xl, s1, 0);
    vsquash_kernel<<<160, 256, 0, stream>>>(s1, vbuf);
    agree_kernel<0><<<I_ / NI, 256, 0, stream>>>(x, W, vbuf, blog, cbuf);
    // ---- iter 3 ----
    spart_kernel<<<288, 256, 0, stream>>>(x, W, cbuf, xh, xl, s2, 0);
    vsquash_kernel<<<160, 256, 0, stream>>>(s2, out);
}